// Round 19
// baseline (116.300 us; speedup 1.0000x reference)
//
#include <hip/hip_runtime.h>
#include <math.h>

#define FH 384
#define FW 384
#define DH 96
#define DW 96
#define NIMG 6   // 0,1: pred b0,b1; 2,3: I[:,0] b0,b1; 4,5: I[:,1] b0,b1
#define PLANE (DH * DW)
#define NPIX (2 * PLANE)

// Keys cubic kernel, a = -0.5 (matches jax.image "cubic")
__device__ __forceinline__ float keysc(float x) {
    if (x < 1.f) return ((1.5f * x - 2.5f) * x) * x + 1.f;
    if (x < 2.f) return ((-0.5f * x + 2.5f) * x - 4.f) * x + 2.f;
    return 0.f;
}

// reflect-101 (jnp.pad mode='reflect'), valid for i in [-(n-1), 2n-2]
__device__ __forceinline__ int refl(int i, int n) {
    if (i < 0) i = -i;
    if (i >= n) i = 2 * (n - 1) - i;
    return i;
}

// ---------------- K1: full-res census fields (gray inline) -----------------
// CF[img][ck][r][x], ck = k<4 ? k : k-1 (channel 4 == center == exactly +0)
__global__ void k_field(const float* __restrict__ pred, const float* __restrict__ I,
                        float* __restrict__ CF) {
    int idx = blockIdx.x * 256 + threadIdx.x;
    const int total = NIMG * FH * FW;
    if (idx >= total) return;
    int x   = idx % FW;
    int t1  = idx / FW;
    int r   = t1 % FH;
    int img = t1 / FH;
    const float* src;
    if (img < 2) {
        src = pred + img * 3 * FH * FW;
    } else {
        int j = (img - 2) >> 1, b = (img - 2) & 1;
        src = I + ((b * 2 + j) * 3) * FH * FW;
    }
    const int planeF = FH * FW;
    auto grayAt = [&](int rr, int cc) -> float {
        const float* s = src + rr * FW + cc;
        return (0.299f * s[0] + 0.587f * s[planeF] + 0.114f * s[2 * planeF]) * 255.0f;
    };
    float gc = grayAt(r, x);
    float* out = CF + ((size_t)img * 8) * planeF + r * FW + x;
    int ck = 0;
#pragma unroll
    for (int k = 0; k < 9; ++k) {
        if (k == 4) continue;
        int dy = k / 3 - 1, dx = k % 3 - 1;
        int r2 = r + dy, c2 = x + dx;
        float gn = (r2 < 0 || r2 >= FH || c2 < 0 || c2 >= FW) ? 0.f : grayAt(r2, c2);
        float tt = gn - gc;   // EXACT softsign expression (keep)
        out[ck * planeF] = tt / sqrtf(0.81f + tt * tt);
        ++ck;
    }
}

// ---------------- K2: H-downsample, 4 yo-outputs per thread, float4 --------
#define CQ (NIMG * 9 * (DH / 4) * (FW / 4))
#define RQ (NIMG * 3 * (DH / 4) * (FW / 4))
__global__ void k_downH(const float* __restrict__ CF, const float* __restrict__ pred,
                        const float* __restrict__ I, float* __restrict__ CH,
                        float* __restrict__ RH) {
    int idx = blockIdx.x * 256 + threadIdx.x;
    if (idx >= CQ + RQ) return;
    const int planeF = FH * FW;

    const float4* F;
    float4* outp;        // first of 4 output rows (stride 96 float4)
    int yo0;
    if (idx < CQ) {
        int x4 = idx % 96;
        int t1 = idx / 96;
        int ys = t1 % (DH / 4);
        int t2 = t1 / (DH / 4);
        int k  = t2 % 9;
        int img = t2 / 9;
        yo0 = ys * 4;
        outp = (float4*)CH + ((img * 9 + k) * DH + yo0) * 96 + x4;
        if (k == 4) {        // center channel: t - gray == +0 exactly
            float4 zz = make_float4(0.f, 0.f, 0.f, 0.f);
#pragma unroll
            for (int q = 0; q < 4; ++q) outp[q * 96] = zz;
            return;
        }
        int ck = (k < 4) ? k : k - 1;
        F = (const float4*)(CF + (size_t)(img * 8 + ck) * planeF) + x4;
    } else {
        int rid = idx - CQ;
        int x4 = rid % 96;
        int t1 = rid / 96;
        int ys = t1 % (DH / 4);
        int t2 = t1 / (DH / 4);
        int c  = t2 % 3;
        int img = t2 / 3;
        yo0 = ys * 4;
        const float* src;
        if (img < 2) {
            src = pred + (img * 3 + c) * planeF;
        } else {
            int j = (img - 2) >> 1, b = (img - 2) & 1;
            src = I + (((b * 2 + j) * 3) + c) * planeF;
        }
        F = (const float4*)src + x4;
        outp = (float4*)RH + ((img * 3 + c) * DH + yo0) * 96 + x4;
    }

    int rbase0 = 4 * yo0 - 6;
    float4 acc0 = make_float4(0.f, 0.f, 0.f, 0.f), acc1 = acc0, acc2 = acc0, acc3 = acc0;
    float z0 = 0.f, z1 = 0.f, z2 = 0.f, z3 = 0.f;
#pragma unroll
    for (int rr = 0; rr < 28; ++rr) {
        int ra = rbase0 + rr;
        bool valid = (ra >= 0 && ra < FH);
        float4 v = make_float4(0.f, 0.f, 0.f, 0.f);
        if (valid) v = F[ra * 96];
        // per-output taps: t = rr - 4q, ascending rr == ascending t (bit-exact)
        { int t = rr;      if (t < 16 && valid)            { float w = keysc(fabsf((float)t - 7.5f) * 0.25f); z0 += w; acc0.x += w * v.x; acc0.y += w * v.y; acc0.z += w * v.z; acc0.w += w * v.w; } }
        { int t = rr - 4;  if (t >= 0 && t < 16 && valid)  { float w = keysc(fabsf((float)t - 7.5f) * 0.25f); z1 += w; acc1.x += w * v.x; acc1.y += w * v.y; acc1.z += w * v.z; acc1.w += w * v.w; } }
        { int t = rr - 8;  if (t >= 0 && t < 16 && valid)  { float w = keysc(fabsf((float)t - 7.5f) * 0.25f); z2 += w; acc2.x += w * v.x; acc2.y += w * v.y; acc2.z += w * v.z; acc2.w += w * v.w; } }
        { int t = rr - 12; if (t >= 0 && t < 16 && valid)  { float w = keysc(fabsf((float)t - 7.5f) * 0.25f); z3 += w; acc3.x += w * v.x; acc3.y += w * v.y; acc3.z += w * v.z; acc3.w += w * v.w; } }
    }
    outp[0]      = make_float4(acc0.x / z0, acc0.y / z0, acc0.z / z0, acc0.w / z0);
    outp[96]     = make_float4(acc1.x / z1, acc1.y / z1, acc1.z / z1, acc1.w / z1);
    outp[2 * 96] = make_float4(acc2.x / z2, acc2.y / z2, acc2.z / z2, acc2.w / z2);
    outp[3 * 96] = make_float4(acc3.x / z3, acc3.y / z3, acc3.z / z3, acc3.w / z3);
}

// ---------------- K3: W-downsample, 4 xo-outputs per thread ----------------
__global__ void k_downW(const float* __restrict__ src, float* __restrict__ dst, int nrows) {
    int idx = blockIdx.x * 256 + threadIdx.x;
    int total = nrows * (DW / 4);
    if (idx >= total) return;
    int xq  = idx % (DW / 4);
    int row = idx / (DW / 4);
    const float* s = src + row * FW;
    int base = 16 * xq - 6;

    float a0 = 0.f, a1 = 0.f, a2 = 0.f, a3 = 0.f;
    float z0 = 0.f, z1 = 0.f, z2 = 0.f, z3 = 0.f;
#pragma unroll
    for (int ii = 0; ii < 28; ++ii) {
        int i = base + ii;
        bool valid = (i >= 0 && i < FW);
        float v = valid ? s[i] : 0.f;
        { int t = ii;      if (t < 16 && valid)           { float w = keysc(fabsf((float)t - 7.5f) * 0.25f); z0 += w; a0 += w * v; } }
        { int t = ii - 4;  if (t >= 0 && t < 16 && valid) { float w = keysc(fabsf((float)t - 7.5f) * 0.25f); z1 += w; a1 += w * v; } }
        { int t = ii - 8;  if (t >= 0 && t < 16 && valid) { float w = keysc(fabsf((float)t - 7.5f) * 0.25f); z2 += w; a2 += w * v; } }
        { int t = ii - 12; if (t >= 0 && t < 16 && valid) { float w = keysc(fabsf((float)t - 7.5f) * 0.25f); z3 += w; a3 += w * v; } }
    }
    float4* o = (float4*)(dst + row * DW) + xq;
    *o = make_float4(a0 / z0, a1 / z1, a2 / z2, a3 / z3);
}

// ---------------- K5: n2 per (neighbor image, position) + counter reset ----
__global__ void k_n2(const float* __restrict__ CD, float* __restrict__ N2,
                     int* __restrict__ counter) {
    int idx = blockIdx.x * 256 + threadIdx.x;
    if (idx == 0) *counter = 0;          // reset for k_combine's last-block-done
    if (idx >= 4 * PLANE) return;
    int img4 = idx / PLANE;
    int pos  = idx % PLANE;
    int y = pos / DW, x = pos % DW;
    int ry[3], rx[3];
#pragma unroll
    for (int kk = 0; kk < 3; ++kk) {
        ry[kk] = refl(y + kk - 1, DH);
        rx[kk] = refl(x + kk - 1, DW);
    }
    const float* C = CD + (2 + img4) * 9 * PLANE;
    float s = 0.f;
#pragma unroll
    for (int c = 0; c < 9; ++c)
#pragma unroll
        for (int ky = 0; ky < 3; ++ky)
#pragma unroll
            for (int kx = 0; kx < 3; ++kx) {
                float v = C[c * PLANE + ry[ky] * DW + rx[kx]];
                s += v * v;
            }
    N2[idx] = s;
}

// ---------------- K6: interior matching, 14 groups, channel-pipelined ------
// register double-buffer: load channel c+1 while FMA-ing channel c.
// FMA order per dot is UNCHANGED (c ascending, rows 0/1/2, kx 0/1/2) -> bit-exact.
#define NGRP 14
__global__ __launch_bounds__(256, 4) void k_match_int(const float* __restrict__ CD,
                                                      const float* __restrict__ N2,
                                                      float* __restrict__ bestd,
                                                      int* __restrict__ bestn) {
    int bid  = blockIdx.x;
    int g    = bid / 72;               // 0..13 -> (j, dy)
    int tile = bid % 72;
    int pid  = tile * 256 + threadIdx.x;   // 0..18431
    int j  = g / 7;
    int dy = g % 7 - 3;
    int b   = pid / PLANE;
    int pos = pid % PLANE;
    int y = pos / DW, x = pos % DW;

    int yy = refl(y + dy, DH);
    int r0 = refl(yy - 1, DH), r1 = yy, r2 = refl(yy + 1, DH);
    int pr0 = refl(y - 1, DH), pr2 = refl(y + 1, DH);
    int xb = min(max(x - 4, 0), DW - 9);   // exact for x in [4,91]
    int xp = min(max(x - 1, 0), DW - 3);

    const float* Cp  = CD + (b * 9) * PLANE;
    const float* Cn  = CD + ((2 + 2 * j + b) * 9) * PLANE;
    const float* N2p = N2 + (2 * j + b) * PLANE;

    float P0[2][3], P1[2][3], P2[2][3];
    float W0[2][9], W1[2][9], W2[2][9];

    // load channel `c` operands into buffer `buf` (all indices compile-time)
    auto loadc = [&](int buf, int c) {
        const float* pc = Cp + c * PLANE;
        const float* nc = Cn + c * PLANE;
#pragma unroll
        for (int kx = 0; kx < 3; ++kx) {
            P0[buf][kx] = pc[pr0 * DW + xp + kx];
            P1[buf][kx] = pc[y   * DW + xp + kx];
            P2[buf][kx] = pc[pr2 * DW + xp + kx];
        }
#pragma unroll
        for (int i = 0; i < 9; ++i) {
            W0[buf][i] = nc[r0 * DW + xb + i];
            W1[buf][i] = nc[r1 * DW + xb + i];
            W2[buf][i] = nc[r2 * DW + xb + i];
        }
    };

    float dot[7];
#pragma unroll
    for (int i = 0; i < 7; ++i) dot[i] = 0.f;

    loadc(0, 0);
#pragma unroll
    for (int c = 0; c < 9; ++c) {
        int cur = c & 1;
        if (c < 8) loadc(cur ^ 1, c + 1);   // prefetch next channel
#pragma unroll
        for (int dx = 0; dx < 7; ++dx) {
            float d = dot[dx];
            d += P0[cur][0] * W0[cur][dx + 0]; d += P0[cur][1] * W0[cur][dx + 1]; d += P0[cur][2] * W0[cur][dx + 2];
            d += P1[cur][0] * W1[cur][dx + 0]; d += P1[cur][1] * W1[cur][dx + 1]; d += P1[cur][2] * W1[cur][dx + 2];
            d += P2[cur][0] * W2[cur][dx + 0]; d += P2[cur][1] * W2[cur][dx + 1]; d += P2[cur][2] * W2[cur][dx + 2];
            dot[dx] = d;
        }
    }

    float best = INFINITY;
    int bn = 1 << 30;
    int nbase = j * 49 + (dy + 3) * 7;
#pragma unroll
    for (int dx = 0; dx < 7; ++dx) {
        int xxc = min(max(x + dx - 3, 0), DW - 1);   // == refl(x+dx) for interior x
        float dis = N2p[yy * DW + xxc] - 2.f * dot[dx];
        if (dis < best) { best = dis; bn = nbase + dx; }   // dx ascending
    }
    if (x >= 4 && x < 92) {
        bestd[g * NPIX + pid] = best;
        bestn[g * NPIX + pid] = bn;
    }
}

// ---------------- K6b: wave-parallel exact recompute for x-edge pixels -----
__global__ __launch_bounds__(256) void k_match_edge(const float* __restrict__ CD,
                                                    const float* __restrict__ N2,
                                                    float* __restrict__ bestd,
                                                    int* __restrict__ bestn) {
    __shared__ float part[4][64];
    __shared__ float disw[4][8];

    int wid  = threadIdx.x >> 6;
    int lane = threadIdx.x & 63;
    int item = blockIdx.x * 4 + wid;     // 0..21503 = g*1536 + pe
    int g  = item / 1536;
    int pe = item % 1536;
    int j = g / 7, dy = g % 7 - 3;
    int b   = pe / 768;
    int rem = pe % 768;
    int y  = rem / 8;
    int xi = rem % 8;
    int x  = (xi < 4) ? xi : 88 + xi;
    int pid = b * PLANE + y * DW + x;
    int yy = refl(y + dy, DH);

    int c = lane / 7, dx = lane % 7;     // valid for lane < 63
    float partial = 0.f;
    if (lane < 63) {
        int xx = refl(x + dx - 3, DW);
        const float* pc = CD + (b * 9 + c) * PLANE;
        const float* nc = CD + ((2 + 2 * j + b) * 9 + c) * PLANE;
#pragma unroll
        for (int ky = 0; ky < 3; ++ky) {
            int pry = refl(y + ky - 1, DH);
            int nry = refl(yy + ky - 1, DH);
#pragma unroll
            for (int kx = 0; kx < 3; ++kx) {
                int prx = refl(x + kx - 1, DW);
                int nrx = refl(xx + kx - 1, DW);
                partial += pc[pry * DW + prx] * nc[nry * DW + nrx];
            }
        }
    }
    part[wid][lane] = partial;
    __syncthreads();

    if (lane < 7) {
        float dot = 0.f;
#pragma unroll
        for (int cc = 0; cc < 9; ++cc) dot += part[wid][cc * 7 + lane];
        int xxl = refl(x + lane - 3, DW);
        disw[wid][lane] = N2[(2 * j + b) * PLANE + yy * DW + xxl] - 2.f * dot;
    }
    __syncthreads();

    if (lane == 0) {
        float best = INFINITY;
        int bn = 1 << 30;
        int nbase = j * 49 + (dy + 3) * 7;
#pragma unroll
        for (int dxx = 0; dxx < 7; ++dxx) {
            float d = disw[wid][dxx];
            if (d < best) { best = d; bn = nbase + dxx; }   // dx ascending
        }
        bestd[g * NPIX + pid] = best;
        bestn[g * NPIX + pid] = bn;
    }
}

// ---------------- K7: combine 14 groups + loss gather + fused final --------
#define NPART 72
__global__ __launch_bounds__(256) void k_combine(const float* __restrict__ bestd,
                                                 const int* __restrict__ bestn,
                                                 const float* __restrict__ RD,
                                                 float* __restrict__ partial,
                                                 int* __restrict__ counter,
                                                 float* __restrict__ out) {
    int pid = blockIdx.x * 256 + threadIdx.x;   // 0..18431
    int b   = pid / PLANE;
    int pos = pid % PLANE;
    int y = pos / DW, x = pos % DW;

    float d0 = bestd[pid];
    int   n0 = bestn[pid];
#pragma unroll
    for (int g = 1; g < NGRP; ++g) {
        float d = bestd[g * NPIX + pid];
        int   n = bestn[g * NPIX + pid];
        if (d < d0 || (d == d0 && n < n0)) { d0 = d; n0 = n; }
    }

    int j = n0 / 49, rr = n0 % 49;
    int dy = rr / 7 - 3, dx = rr % 7 - 3;
    int yy = refl(y + dy, DH), xx = refl(x + dx, DW);
    int ry0[3], rx0[3], ry[3], rx[3];
#pragma unroll
    for (int kk = 0; kk < 3; ++kk) {
        ry0[kk] = refl(y + kk - 1, DH);
        rx0[kk] = refl(x + kk - 1, DW);
        ry[kk]  = refl(yy + kk - 1, DH);
        rx[kk]  = refl(xx + kk - 1, DW);
    }
    const float* RDp = RD + b * 3 * PLANE;
    const float* RDn = RD + (2 + 2 * j + b) * 3 * PLANE;
    float loss = 0.f;
#pragma unroll
    for (int c = 0; c < 3; ++c)
#pragma unroll
        for (int ky = 0; ky < 3; ++ky)
#pragma unroll
            for (int kx = 0; kx < 3; ++kx) {
                float a = RDp[c * PLANE + ry0[ky] * DW + rx0[kx]];
                float m = RDn[c * PLANE + ry[ky] * DW + rx[kx]];
                float d = a - m;
                loss += d * d;
            }

    __shared__ float red[256];
    __shared__ int sdone;
    red[threadIdx.x] = loss;
    __syncthreads();
#pragma unroll
    for (int s = 128; s > 0; s >>= 1) {
        if (threadIdx.x < s) red[threadIdx.x] += red[threadIdx.x + s];
        __syncthreads();
    }
    if (threadIdx.x == 0) {
        __hip_atomic_store(&partial[blockIdx.x], red[0], __ATOMIC_RELEASE,
                           __HIP_MEMORY_SCOPE_AGENT);
        int prev = __hip_atomic_fetch_add(counter, 1, __ATOMIC_ACQ_REL,
                                          __HIP_MEMORY_SCOPE_AGENT);
        sdone = (prev == NPART - 1);
    }
    __syncthreads();

    if (sdone) {
        // exact replica of old k_final's 128-wide tree (bit-identical order)
        __shared__ float red2[128];
        if (threadIdx.x < 128) {
            float v = (threadIdx.x < NPART)
                ? __hip_atomic_load(&partial[threadIdx.x], __ATOMIC_ACQUIRE,
                                    __HIP_MEMORY_SCOPE_AGENT)
                : 0.f;
            red2[threadIdx.x] = v;
        }
        __syncthreads();
#pragma unroll
        for (int s = 64; s > 0; s >>= 1) {
            if (threadIdx.x < s) red2[threadIdx.x] += red2[threadIdx.x + s];
            __syncthreads();
        }
        if (threadIdx.x == 0) out[0] = red2[0] * (0.5f / 497664.0f);
    }
}

extern "C" void kernel_launch(void* const* d_in, const int* in_sizes, int n_in,
                              void* d_out, int out_size, void* d_ws, size_t ws_size,
                              hipStream_t stream) {
    const float* pred = (const float*)d_in[0];   // [2,3,384,384]
    const float* I    = (const float*)d_in[1];   // [2,2,3,384,384]
    float* out = (float*)d_out;
    float* ws  = (float*)d_ws;

    // workspace layout (floats):
    //   CD   [0, 497664)                 6*9*96*96
    //   RD   [497664, 663552)            6*3*96*96
    //   S = 663552:
    //     CF  [S, S+7077888)             6*8*384*384  (dead after downH)
    //     CH  [S+7077888, S+9068544)     6*9*96*384   (dead after downW)
    //     RH  [S+9068544, S+9732096)     6*3*96*384   (dead after downW)
    //   reused after downW (inside dead CF region):
    //     N2      [S, S+36864)           4*9216
    //     bestd   [S+36864, S+294912)    14*18432
    //     bestn   [S+294912, S+552960)   14*18432 (int)
    //     part    [S+552960, S+553032)   72
    //     counter [S+553032]             1 (int)
    float* CD   = ws;
    float* RD   = CD + 497664;
    float* S    = RD + 165888;
    float* CF   = S;
    float* CH   = S + 7077888;
    float* RH   = S + 9068544;
    float* N2   = S;
    float* bestd = S + 36864;
    int*   bestn = (int*)(S + 294912);
    float* part  = S + 552960;
    int*   counter = (int*)(S + 553032);

    k_field<<<(NIMG * FH * FW + 255) / 256, 256, 0, stream>>>(pred, I, CF);
    k_downH<<<(CQ + RQ + 255) / 256, 256, 0, stream>>>(CF, pred, I, CH, RH);
    k_downW<<<((NIMG * 12 * DH) * (DW / 4) + 255) / 256, 256, 0, stream>>>(CH, CD, NIMG * 12 * DH);
    k_n2<<<(4 * PLANE + 255) / 256, 256, 0, stream>>>(CD, N2, counter);
    k_match_int<<<NGRP * 72, 256, 0, stream>>>(CD, N2, bestd, bestn);
    k_match_edge<<<(14 * 1536) / 4, 256, 0, stream>>>(CD, N2, bestd, bestn);
    k_combine<<<NPIX / 256, 256, 0, stream>>>(bestd, bestn, RD, part, counter, out);
}

// Round 20
// 114.484 us; speedup vs baseline: 1.0159x; 1.0159x over previous
//
#include <hip/hip_runtime.h>
#include <math.h>

#define FH 384
#define FW 384
#define DH 96
#define DW 96
#define NIMG 6   // 0,1: pred b0,b1; 2,3: I[:,0] b0,b1; 4,5: I[:,1] b0,b1
#define PLANE (DH * DW)
#define NPIX (2 * PLANE)

// Keys cubic kernel, a = -0.5 (matches jax.image "cubic")
__device__ __forceinline__ float keysc(float x) {
    if (x < 1.f) return ((1.5f * x - 2.5f) * x) * x + 1.f;
    if (x < 2.f) return ((-0.5f * x + 2.5f) * x - 4.f) * x + 2.f;
    return 0.f;
}

// reflect-101 (jnp.pad mode='reflect'), valid for i in [-(n-1), 2n-2]
__device__ __forceinline__ int refl(int i, int n) {
    if (i < 0) i = -i;
    if (i >= n) i = 2 * (n - 1) - i;
    return i;
}

// ---------------- K1: full-res census fields (gray inline) -----------------
// CF[img][ck][r][x], ck = k<4 ? k : k-1 (channel 4 == center == exactly +0)
__global__ void k_field(const float* __restrict__ pred, const float* __restrict__ I,
                        float* __restrict__ CF) {
    int idx = blockIdx.x * 256 + threadIdx.x;
    const int total = NIMG * FH * FW;
    if (idx >= total) return;
    int x   = idx % FW;
    int t1  = idx / FW;
    int r   = t1 % FH;
    int img = t1 / FH;
    const float* src;
    if (img < 2) {
        src = pred + img * 3 * FH * FW;
    } else {
        int j = (img - 2) >> 1, b = (img - 2) & 1;
        src = I + ((b * 2 + j) * 3) * FH * FW;
    }
    const int planeF = FH * FW;
    auto grayAt = [&](int rr, int cc) -> float {
        const float* s = src + rr * FW + cc;
        return (0.299f * s[0] + 0.587f * s[planeF] + 0.114f * s[2 * planeF]) * 255.0f;
    };
    float gc = grayAt(r, x);
    float* out = CF + ((size_t)img * 8) * planeF + r * FW + x;
    int ck = 0;
#pragma unroll
    for (int k = 0; k < 9; ++k) {
        if (k == 4) continue;
        int dy = k / 3 - 1, dx = k % 3 - 1;
        int r2 = r + dy, c2 = x + dx;
        float gn = (r2 < 0 || r2 >= FH || c2 < 0 || c2 >= FW) ? 0.f : grayAt(r2, c2);
        float tt = gn - gc;   // EXACT softsign expression (keep)
        out[ck * planeF] = tt / sqrtf(0.81f + tt * tt);
        ++ck;
    }
}

// ---------------- K2: H-downsample, 4 yo-outputs per thread, float4 --------
#define CQ (NIMG * 9 * (DH / 4) * (FW / 4))
#define RQ (NIMG * 3 * (DH / 4) * (FW / 4))
__global__ void k_downH(const float* __restrict__ CF, const float* __restrict__ pred,
                        const float* __restrict__ I, float* __restrict__ CH,
                        float* __restrict__ RH) {
    int idx = blockIdx.x * 256 + threadIdx.x;
    if (idx >= CQ + RQ) return;
    const int planeF = FH * FW;

    const float4* F;
    float4* outp;        // first of 4 output rows (stride 96 float4)
    int yo0;
    if (idx < CQ) {
        int x4 = idx % 96;
        int t1 = idx / 96;
        int ys = t1 % (DH / 4);
        int t2 = t1 / (DH / 4);
        int k  = t2 % 9;
        int img = t2 / 9;
        yo0 = ys * 4;
        outp = (float4*)CH + ((img * 9 + k) * DH + yo0) * 96 + x4;
        if (k == 4) {        // center channel: t - gray == +0 exactly
            float4 zz = make_float4(0.f, 0.f, 0.f, 0.f);
#pragma unroll
            for (int q = 0; q < 4; ++q) outp[q * 96] = zz;
            return;
        }
        int ck = (k < 4) ? k : k - 1;
        F = (const float4*)(CF + (size_t)(img * 8 + ck) * planeF) + x4;
    } else {
        int rid = idx - CQ;
        int x4 = rid % 96;
        int t1 = rid / 96;
        int ys = t1 % (DH / 4);
        int t2 = t1 / (DH / 4);
        int c  = t2 % 3;
        int img = t2 / 3;
        yo0 = ys * 4;
        const float* src;
        if (img < 2) {
            src = pred + (img * 3 + c) * planeF;
        } else {
            int j = (img - 2) >> 1, b = (img - 2) & 1;
            src = I + (((b * 2 + j) * 3) + c) * planeF;
        }
        F = (const float4*)src + x4;
        outp = (float4*)RH + ((img * 3 + c) * DH + yo0) * 96 + x4;
    }

    int rbase0 = 4 * yo0 - 6;
    float4 acc0 = make_float4(0.f, 0.f, 0.f, 0.f), acc1 = acc0, acc2 = acc0, acc3 = acc0;
    float z0 = 0.f, z1 = 0.f, z2 = 0.f, z3 = 0.f;
#pragma unroll
    for (int rr = 0; rr < 28; ++rr) {
        int ra = rbase0 + rr;
        bool valid = (ra >= 0 && ra < FH);
        float4 v = make_float4(0.f, 0.f, 0.f, 0.f);
        if (valid) v = F[ra * 96];
        // per-output taps: t = rr - 4q, ascending rr == ascending t (bit-exact)
        { int t = rr;      if (t < 16 && valid)            { float w = keysc(fabsf((float)t - 7.5f) * 0.25f); z0 += w; acc0.x += w * v.x; acc0.y += w * v.y; acc0.z += w * v.z; acc0.w += w * v.w; } }
        { int t = rr - 4;  if (t >= 0 && t < 16 && valid)  { float w = keysc(fabsf((float)t - 7.5f) * 0.25f); z1 += w; acc1.x += w * v.x; acc1.y += w * v.y; acc1.z += w * v.z; acc1.w += w * v.w; } }
        { int t = rr - 8;  if (t >= 0 && t < 16 && valid)  { float w = keysc(fabsf((float)t - 7.5f) * 0.25f); z2 += w; acc2.x += w * v.x; acc2.y += w * v.y; acc2.z += w * v.z; acc2.w += w * v.w; } }
        { int t = rr - 12; if (t >= 0 && t < 16 && valid)  { float w = keysc(fabsf((float)t - 7.5f) * 0.25f); z3 += w; acc3.x += w * v.x; acc3.y += w * v.y; acc3.z += w * v.z; acc3.w += w * v.w; } }
    }
    outp[0]      = make_float4(acc0.x / z0, acc0.y / z0, acc0.z / z0, acc0.w / z0);
    outp[96]     = make_float4(acc1.x / z1, acc1.y / z1, acc1.z / z1, acc1.w / z1);
    outp[2 * 96] = make_float4(acc2.x / z2, acc2.y / z2, acc2.z / z2, acc2.w / z2);
    outp[3 * 96] = make_float4(acc3.x / z3, acc3.y / z3, acc3.z / z3, acc3.w / z3);
}

// ---------------- K3: W-downsample, 4 xo-outputs per thread ----------------
__global__ void k_downW(const float* __restrict__ src, float* __restrict__ dst, int nrows) {
    int idx = blockIdx.x * 256 + threadIdx.x;
    int total = nrows * (DW / 4);
    if (idx >= total) return;
    int xq  = idx % (DW / 4);
    int row = idx / (DW / 4);
    const float* s = src + row * FW;
    int base = 16 * xq - 6;

    float a0 = 0.f, a1 = 0.f, a2 = 0.f, a3 = 0.f;
    float z0 = 0.f, z1 = 0.f, z2 = 0.f, z3 = 0.f;
#pragma unroll
    for (int ii = 0; ii < 28; ++ii) {
        int i = base + ii;
        bool valid = (i >= 0 && i < FW);
        float v = valid ? s[i] : 0.f;
        { int t = ii;      if (t < 16 && valid)           { float w = keysc(fabsf((float)t - 7.5f) * 0.25f); z0 += w; a0 += w * v; } }
        { int t = ii - 4;  if (t >= 0 && t < 16 && valid) { float w = keysc(fabsf((float)t - 7.5f) * 0.25f); z1 += w; a1 += w * v; } }
        { int t = ii - 8;  if (t >= 0 && t < 16 && valid) { float w = keysc(fabsf((float)t - 7.5f) * 0.25f); z2 += w; a2 += w * v; } }
        { int t = ii - 12; if (t >= 0 && t < 16 && valid) { float w = keysc(fabsf((float)t - 7.5f) * 0.25f); z3 += w; a3 += w * v; } }
    }
    float4* o = (float4*)(dst + row * DW) + xq;
    *o = make_float4(a0 / z0, a1 / z1, a2 / z2, a3 / z3);
}

// ---------------- K5: n2 per (neighbor image, position) + counter reset ----
__global__ void k_n2(const float* __restrict__ CD, float* __restrict__ N2,
                     int* __restrict__ counter) {
    int idx = blockIdx.x * 256 + threadIdx.x;
    if (idx == 0) *counter = 0;          // reset for k_combine's last-block-done
    if (idx >= 4 * PLANE) return;
    int img4 = idx / PLANE;
    int pos  = idx % PLANE;
    int y = pos / DW, x = pos % DW;
    int ry[3], rx[3];
#pragma unroll
    for (int kk = 0; kk < 3; ++kk) {
        ry[kk] = refl(y + kk - 1, DH);
        rx[kk] = refl(x + kk - 1, DW);
    }
    const float* C = CD + (2 + img4) * 9 * PLANE;
    float s = 0.f;
#pragma unroll
    for (int c = 0; c < 9; ++c)
#pragma unroll
        for (int ky = 0; ky < 3; ++ky)
#pragma unroll
            for (int kx = 0; kx < 3; ++kx) {
                float v = C[c * PLANE + ry[ky] * DW + rx[kx]];
                s += v * v;
            }
    N2[idx] = s;
}

// ---------------- K6: interior matching, 14 groups (j, dy) -----------------
// stores only interior x (4..91); edge pids owned by k_match_edge
#define NGRP 14
__global__ __launch_bounds__(256) void k_match_int(const float* __restrict__ CD,
                                                   const float* __restrict__ N2,
                                                   float* __restrict__ bestd,
                                                   int* __restrict__ bestn) {
    int bid  = blockIdx.x;
    int g    = bid / 72;               // 0..13 -> (j, dy)
    int tile = bid % 72;
    int pid  = tile * 256 + threadIdx.x;   // 0..18431
    int j  = g / 7;
    int dy = g % 7 - 3;
    int b   = pid / PLANE;
    int pos = pid % PLANE;
    int y = pos / DW, x = pos % DW;

    int yy = refl(y + dy, DH);
    int r0 = refl(yy - 1, DH), r1 = yy, r2 = refl(yy + 1, DH);
    int pr0 = refl(y - 1, DH), pr2 = refl(y + 1, DH);
    int xb = min(max(x - 4, 0), DW - 9);   // exact for x in [4,91]
    int xp = min(max(x - 1, 0), DW - 3);

    const float* Cp  = CD + (b * 9) * PLANE;
    const float* Cn  = CD + ((2 + 2 * j + b) * 9) * PLANE;
    const float* N2p = N2 + (2 * j + b) * PLANE;

    float dot[7];
#pragma unroll
    for (int i = 0; i < 7; ++i) dot[i] = 0.f;

#pragma unroll
    for (int c = 0; c < 9; ++c) {
        const float* pc = Cp + c * PLANE;
        const float* nc = Cn + c * PLANE;
        float p0[3], p1[3], p2[3];
#pragma unroll
        for (int kx = 0; kx < 3; ++kx) {
            p0[kx] = pc[pr0 * DW + xp + kx];
            p1[kx] = pc[y   * DW + xp + kx];
            p2[kx] = pc[pr2 * DW + xp + kx];
        }
        float w0[9], w1[9], w2[9];
#pragma unroll
        for (int i = 0; i < 9; ++i) {
            w0[i] = nc[r0 * DW + xb + i];
            w1[i] = nc[r1 * DW + xb + i];
            w2[i] = nc[r2 * DW + xb + i];
        }
#pragma unroll
        for (int dx = 0; dx < 7; ++dx) {
            float d = dot[dx];
            d += p0[0] * w0[dx + 0]; d += p0[1] * w0[dx + 1]; d += p0[2] * w0[dx + 2];
            d += p1[0] * w1[dx + 0]; d += p1[1] * w1[dx + 1]; d += p1[2] * w1[dx + 2];
            d += p2[0] * w2[dx + 0]; d += p2[1] * w2[dx + 1]; d += p2[2] * w2[dx + 2];
            dot[dx] = d;
        }
    }

    float best = INFINITY;
    int bn = 1 << 30;
    int nbase = j * 49 + (dy + 3) * 7;
#pragma unroll
    for (int dx = 0; dx < 7; ++dx) {
        int xxc = min(max(x + dx - 3, 0), DW - 1);   // == refl(x+dx) for interior x
        float dis = N2p[yy * DW + xxc] - 2.f * dot[dx];
        if (dis < best) { best = dis; bn = nbase + dx; }   // dx ascending
    }
    if (x >= 4 && x < 92) {
        bestd[g * NPIX + pid] = best;
        bestn[g * NPIX + pid] = bn;
    }
}

// ---------------- K6b: wave-parallel exact recompute for x-edge pixels -----
// one wave per (g, edge pixel); 21504 items, 4 waves/block -> 5376 blocks
__global__ __launch_bounds__(256) void k_match_edge(const float* __restrict__ CD,
                                                    const float* __restrict__ N2,
                                                    float* __restrict__ bestd,
                                                    int* __restrict__ bestn) {
    __shared__ float part[4][64];
    __shared__ float disw[4][8];

    int wid  = threadIdx.x >> 6;
    int lane = threadIdx.x & 63;
    int item = blockIdx.x * 4 + wid;     // 0..21503 = g*1536 + pe
    int g  = item / 1536;
    int pe = item % 1536;
    int j = g / 7, dy = g % 7 - 3;
    int b   = pe / 768;
    int rem = pe % 768;
    int y  = rem / 8;
    int xi = rem % 8;
    int x  = (xi < 4) ? xi : 88 + xi;
    int pid = b * PLANE + y * DW + x;
    int yy = refl(y + dy, DH);

    int c = lane / 7, dx = lane % 7;     // valid for lane < 63
    float partial = 0.f;
    if (lane < 63) {
        int xx = refl(x + dx - 3, DW);
        const float* pc = CD + (b * 9 + c) * PLANE;
        const float* nc = CD + ((2 + 2 * j + b) * 9 + c) * PLANE;
#pragma unroll
        for (int ky = 0; ky < 3; ++ky) {
            int pry = refl(y + ky - 1, DH);
            int nry = refl(yy + ky - 1, DH);
#pragma unroll
            for (int kx = 0; kx < 3; ++kx) {
                int prx = refl(x + kx - 1, DW);
                int nrx = refl(xx + kx - 1, DW);
                partial += pc[pry * DW + prx] * nc[nry * DW + nrx];
            }
        }
    }
    part[wid][lane] = partial;
    __syncthreads();

    if (lane < 7) {
        float dot = 0.f;
#pragma unroll
        for (int cc = 0; cc < 9; ++cc) dot += part[wid][cc * 7 + lane];
        int xxl = refl(x + lane - 3, DW);
        disw[wid][lane] = N2[(2 * j + b) * PLANE + yy * DW + xxl] - 2.f * dot;
    }
    __syncthreads();

    if (lane == 0) {
        float best = INFINITY;
        int bn = 1 << 30;
        int nbase = j * 49 + (dy + 3) * 7;
#pragma unroll
        for (int dxx = 0; dxx < 7; ++dxx) {
            float d = disw[wid][dxx];
            if (d < best) { best = d; bn = nbase + dxx; }   // dx ascending
        }
        bestd[g * NPIX + pid] = best;
        bestn[g * NPIX + pid] = bn;
    }
}

// ---------------- K7: combine 14 groups + loss gather + fused final --------
#define NPART 72
__global__ __launch_bounds__(256) void k_combine(const float* __restrict__ bestd,
                                                 const int* __restrict__ bestn,
                                                 const float* __restrict__ RD,
                                                 float* __restrict__ partial,
                                                 int* __restrict__ counter,
                                                 float* __restrict__ out) {
    int pid = blockIdx.x * 256 + threadIdx.x;   // 0..18431
    int b   = pid / PLANE;
    int pos = pid % PLANE;
    int y = pos / DW, x = pos % DW;

    float d0 = bestd[pid];
    int   n0 = bestn[pid];
#pragma unroll
    for (int g = 1; g < NGRP; ++g) {
        float d = bestd[g * NPIX + pid];
        int   n = bestn[g * NPIX + pid];
        if (d < d0 || (d == d0 && n < n0)) { d0 = d; n0 = n; }
    }

    int j = n0 / 49, rr = n0 % 49;
    int dy = rr / 7 - 3, dx = rr % 7 - 3;
    int yy = refl(y + dy, DH), xx = refl(x + dx, DW);
    int ry0[3], rx0[3], ry[3], rx[3];
#pragma unroll
    for (int kk = 0; kk < 3; ++kk) {
        ry0[kk] = refl(y + kk - 1, DH);
        rx0[kk] = refl(x + kk - 1, DW);
        ry[kk]  = refl(yy + kk - 1, DH);
        rx[kk]  = refl(xx + kk - 1, DW);
    }
    const float* RDp = RD + b * 3 * PLANE;
    const float* RDn = RD + (2 + 2 * j + b) * 3 * PLANE;
    float loss = 0.f;
#pragma unroll
    for (int c = 0; c < 3; ++c)
#pragma unroll
        for (int ky = 0; ky < 3; ++ky)
#pragma unroll
            for (int kx = 0; kx < 3; ++kx) {
                float a = RDp[c * PLANE + ry0[ky] * DW + rx0[kx]];
                float m = RDn[c * PLANE + ry[ky] * DW + rx[kx]];
                float d = a - m;
                loss += d * d;
            }

    __shared__ float red[256];
    __shared__ int sdone;
    red[threadIdx.x] = loss;
    __syncthreads();
#pragma unroll
    for (int s = 128; s > 0; s >>= 1) {
        if (threadIdx.x < s) red[threadIdx.x] += red[threadIdx.x + s];
        __syncthreads();
    }
    if (threadIdx.x == 0) {
        __hip_atomic_store(&partial[blockIdx.x], red[0], __ATOMIC_RELEASE,
                           __HIP_MEMORY_SCOPE_AGENT);
        int prev = __hip_atomic_fetch_add(counter, 1, __ATOMIC_ACQ_REL,
                                          __HIP_MEMORY_SCOPE_AGENT);
        sdone = (prev == NPART - 1);
    }
    __syncthreads();

    if (sdone) {
        // exact replica of old k_final's 128-wide tree (bit-identical order)
        __shared__ float red2[128];
        if (threadIdx.x < 128) {
            float v = (threadIdx.x < NPART)
                ? __hip_atomic_load(&partial[threadIdx.x], __ATOMIC_ACQUIRE,
                                    __HIP_MEMORY_SCOPE_AGENT)
                : 0.f;
            red2[threadIdx.x] = v;
        }
        __syncthreads();
#pragma unroll
        for (int s = 64; s > 0; s >>= 1) {
            if (threadIdx.x < s) red2[threadIdx.x] += red2[threadIdx.x + s];
            __syncthreads();
        }
        if (threadIdx.x == 0) out[0] = red2[0] * (0.5f / 497664.0f);
    }
}

extern "C" void kernel_launch(void* const* d_in, const int* in_sizes, int n_in,
                              void* d_out, int out_size, void* d_ws, size_t ws_size,
                              hipStream_t stream) {
    const float* pred = (const float*)d_in[0];   // [2,3,384,384]
    const float* I    = (const float*)d_in[1];   // [2,2,3,384,384]
    float* out = (float*)d_out;
    float* ws  = (float*)d_ws;

    // workspace layout (floats):
    //   CD   [0, 497664)                 6*9*96*96
    //   RD   [497664, 663552)            6*3*96*96
    //   S = 663552:
    //     CF  [S, S+7077888)             6*8*384*384  (dead after downH)
    //     CH  [S+7077888, S+9068544)     6*9*96*384   (dead after downW)
    //     RH  [S+9068544, S+9732096)     6*3*96*384   (dead after downW)
    //   reused after downW (inside dead CF region):
    //     N2      [S, S+36864)           4*9216
    //     bestd   [S+36864, S+294912)    14*18432
    //     bestn   [S+294912, S+552960)   14*18432 (int)
    //     part    [S+552960, S+553032)   72
    //     counter [S+553032]             1 (int)
    float* CD   = ws;
    float* RD   = CD + 497664;
    float* S    = RD + 165888;
    float* CF   = S;
    float* CH   = S + 7077888;
    float* RH   = S + 9068544;
    float* N2   = S;
    float* bestd = S + 36864;
    int*   bestn = (int*)(S + 294912);
    float* part  = S + 552960;
    int*   counter = (int*)(S + 553032);

    k_field<<<(NIMG * FH * FW + 255) / 256, 256, 0, stream>>>(pred, I, CF);
    k_downH<<<(CQ + RQ + 255) / 256, 256, 0, stream>>>(CF, pred, I, CH, RH);
    k_downW<<<((NIMG * 12 * DH) * (DW / 4) + 255) / 256, 256, 0, stream>>>(CH, CD, NIMG * 12 * DH);
    k_n2<<<(4 * PLANE + 255) / 256, 256, 0, stream>>>(CD, N2, counter);
    k_match_int<<<NGRP * 72, 256, 0, stream>>>(CD, N2, bestd, bestn);
    k_match_edge<<<(14 * 1536) / 4, 256, 0, stream>>>(CD, N2, bestd, bestn);
    k_combine<<<NPIX / 256, 256, 0, stream>>>(bestd, bestn, RD, part, counter, out);
}